// Round 3
// baseline (2195.301 us; speedup 1.0000x reference)
//
#include <hip/hip_runtime.h>

#define B_ 8
#define H_ 256
#define W_ 256
#define U_ 64
#define NROW (B_ * H_)           // 2048 rows total
#define NPIX (B_ * H_ * W_)      // 524288 pixels
#define DEPTH 16                 // LDS ring depth (power of 2)
#define WPB 8                    // waves (rows) per block
#define NBLK (NROW / WPB)        // 256 blocks == 256 CUs

__device__ __forceinline__ void lgkm_wait() {
  asm volatile("s_waitcnt lgkmcnt(0)" ::: "memory");
  __builtin_amdgcn_sched_barrier(0);
}

// ---------------- Phase 1: x_proj = x @ Wx + b, written in-place into out ----
__global__ __launch_bounds__(256) void xproj_kernel(
    const float* __restrict__ x, const float* __restrict__ Wx,
    const float* __restrict__ bias, float* __restrict__ out) {
  __shared__ float xs[4][64];
  const int wv = threadIdx.x >> 6;
  const int u  = threadIdx.x & 63;

  float wx[64];
#pragma unroll
  for (int k = 0; k < 64; ++k) wx[k] = Wx[k * 64 + u];  // column u of Wx
  const float bu = bias[u];

  const int stride = gridDim.x * 4;
  for (int n = blockIdx.x * 4 + wv; n < NPIX; n += stride) {
    xs[wv][u] = x[(size_t)n * 64 + u];   // stage pixel vector (coalesced)
    lgkm_wait();
    float a0 = bu, a1 = 0.f, a2 = 0.f, a3 = 0.f;
    const float4* xv4 = (const float4*)(&xs[wv][0]);
#pragma unroll
    for (int kk = 0; kk < 16; ++kk) {    // uniform-address b128 broadcasts
      float4 v = xv4[kk];
      a0 = fmaf(v.x, wx[4 * kk + 0], a0);
      a1 = fmaf(v.y, wx[4 * kk + 1], a1);
      a2 = fmaf(v.z, wx[4 * kk + 2], a2);
      a3 = fmaf(v.w, wx[4 * kk + 3], a3);
    }
    out[(size_t)n * 64 + u] = (a0 + a1) + (a2 + a3);
  }
}

// ---------------- Phase 2: cooperative pipelined 2D recurrence ---------------
// Block = 8 consecutive rows of one batch image. Intra-block row handoffs via
// an LDS ring (DEPTH slots/row); cross-block handoffs (every 8th row) via
// agent-scope atomics with a delayed-flag release protocol. Cooperative
// launch guarantees all 256 blocks co-resident -> spin-waits cannot deadlock.
__global__ __launch_bounds__(512, 2) void mdrnn_kernel(
    const float* __restrict__ Wu_g, const float* __restrict__ Wl_g,
    float* out, int* gflag) {
  __shared__ float ring[WPB][DEPTH][U_];
  __shared__ float upstage[2][U_];      // wave0 cross-block staging (dbuf)
  __shared__ int prodf[WPB];
  __shared__ int consf[WPB];

  const int wv = threadIdx.x >> 6;
  const int u  = threadIdx.x & 63;
  const int bk = blockIdx.x;
  const int b  = bk >> 5;                    // batch
  const int r  = ((bk & 31) << 3) + wv;      // row in image
  const bool top      = (r == 0);
  const bool wave0    = (wv == 0);
  const bool wave7    = (wv == WPB - 1);
  const bool has_down = wave7 && (r < H_ - 1);

  float wu[U_], wl[U_];
#pragma unroll
  for (int k = 0; k < U_; ++k) {
    wu[k] = Wu_g[k * U_ + u];  // column u of Wu
    wl[k] = Wl_g[k * U_ + u];  // column u of Wl
  }

  float* myrow = out + (size_t)(b * H_ + r) * (W_ * U_);
  const float* uprow = out + (size_t)(b * H_ + r - 1) * (W_ * U_);
  int* myflag = gflag + b * H_ + r;
  int* upflag = gflag + b * H_ + r - 1;

  // ---- init LDS
  ring[wv][DEPTH - 1][u] = 0.f;              // left vector for j==0
  if (wv == 0) { upstage[0][u] = 0.f; upstage[1][u] = 0.f; }
  if (threadIdx.x < WPB) { prodf[threadIdx.x] = 0; consf[threadIdx.x] = 0; }
  __syncthreads();

  int gseen = 0, pseen = 0, cseen = 0;
  float xpv = myrow[u];                      // x_proj for cell 0
  float upv_reg = 0.f;

  if (wave0 && !top) {                       // stage cross-block up for cell 0
    while ((gseen = __hip_atomic_load(upflag, __ATOMIC_RELAXED,
                                      __HIP_MEMORY_SCOPE_AGENT)) < 1)
      __builtin_amdgcn_s_sleep(1);
    __builtin_amdgcn_fence(__ATOMIC_ACQUIRE, "agent");
    upstage[0][u] = __hip_atomic_load(uprow + u, __ATOMIC_RELAXED,
                                      __HIP_MEMORY_SCOPE_AGENT);
  }

  for (int j = 0; j < W_; ++j) {
    // ---- A: wait for up-row cell j (intra-block ring)
    if (!wave0) {
      if (pseen < j + 1) {
        while ((pseen = __hip_atomic_load(&prodf[wv - 1], __ATOMIC_RELAXED,
                                          __HIP_MEMORY_SCOPE_WORKGROUP)) < j + 1) {}
      }
      __builtin_amdgcn_fence(__ATOMIC_ACQUIRE, "workgroup");
    }
    const float* upp = wave0 ? &upstage[j & 1][0]
                             : &ring[wv - 1][j & (DEPTH - 1)][0];
    const float* lfp = &ring[wv][(j + DEPTH - 1) & (DEPTH - 1)][0];

    // ---- ring back-pressure: don't overwrite a slot the consumer hasn't read
    if (!wave7 && j >= DEPTH) {
      const int need = j - DEPTH + 1;
      if (cseen < need) {
        while ((cseen = __hip_atomic_load(&consf[wv], __ATOMIC_RELAXED,
                                          __HIP_MEMORY_SCOPE_WORKGROUP)) < need) {}
      }
    }

    // ---- B: prefetch next cell's inputs (latency hidden by FMAs)
    float xpv_n = 0.f;
    bool stage_next = false;
    if (j < W_ - 1) {
      xpv_n = myrow[(size_t)(j + 1) * U_ + u];
      if (wave0 && !top) {
        if (gseen < j + 2) {
          while ((gseen = __hip_atomic_load(upflag, __ATOMIC_RELAXED,
                                            __HIP_MEMORY_SCOPE_AGENT)) < j + 2)
            __builtin_amdgcn_s_sleep(1);
        }
        __builtin_amdgcn_fence(__ATOMIC_ACQUIRE, "agent");
        upv_reg = __hip_atomic_load(uprow + (size_t)(j + 1) * U_ + u,
                                    __ATOMIC_RELAXED, __HIP_MEMORY_SCOPE_AGENT);
        stage_next = true;
      }
    }

    // ---- C: cell compute (uniform-address LDS broadcasts, conflict-free)
    float a0 = xpv, a1 = 0.f, a2 = 0.f, a3 = 0.f;
    const float4* up4 = (const float4*)upp;
    const float4* lf4 = (const float4*)lfp;
#pragma unroll
    for (int kk = 0; kk < 16; ++kk) {
      float4 uv = up4[kk];
      float4 lv = lf4[kk];
      a0 = fmaf(uv.x, wu[4 * kk + 0], a0);
      a1 = fmaf(uv.y, wu[4 * kk + 1], a1);
      a2 = fmaf(uv.z, wu[4 * kk + 2], a2);
      a3 = fmaf(uv.w, wu[4 * kk + 3], a3);
      a0 = fmaf(lv.x, wl[4 * kk + 0], a0);
      a1 = fmaf(lv.y, wl[4 * kk + 1], a1);
      a2 = fmaf(lv.z, wl[4 * kk + 2], a2);
      a3 = fmaf(lv.w, wl[4 * kk + 3], a3);
    }
    const float aout = tanhf((a0 + a1) + (a2 + a3));

    // ---- D: publish — LDS ring FIRST (consumer wake latency is critical
    // path), then ONE workgroup release fence ordering {this cell's ring
    // reads, the ring write} before BOTH flag stores (prodf + consf ack).
    ring[wv][j & (DEPTH - 1)][u] = aout;
    __builtin_amdgcn_fence(__ATOMIC_RELEASE, "workgroup");
    if (u == 0) {
      if (!wave7)
        __hip_atomic_store(&prodf[wv], j + 1, __ATOMIC_RELAXED,
                           __HIP_MEMORY_SCOPE_WORKGROUP);
      if (!wave0)                            // ack consumption of up cell j
        __hip_atomic_store(&consf[wv - 1], j + 1, __ATOMIC_RELAXED,
                           __HIP_MEMORY_SCOPE_WORKGROUP);
    }

    // ---- E: global output store (+ cross-block delayed-flag for wave7)
    if (has_down) {
      // delayed-flag: agent fence drains stores issued >=1 cell ago (cheap),
      // then flag j covers cells 0..j-1, then issue cell j's store.
      __builtin_amdgcn_fence(__ATOMIC_RELEASE, "agent");
      if (u == 0 && j > 0)
        __hip_atomic_store(myflag, j, __ATOMIC_RELAXED,
                           __HIP_MEMORY_SCOPE_AGENT);
      __hip_atomic_store(myrow + (size_t)j * U_ + u, aout, __ATOMIC_RELAXED,
                         __HIP_MEMORY_SCOPE_AGENT);
    } else {
      myrow[(size_t)j * U_ + u] = aout;      // plain output store
    }

    if (stage_next) upstage[(j + 1) & 1][u] = upv_reg;
    xpv = xpv_n;
  }

  if (has_down) {                            // final drain + last flag
    __builtin_amdgcn_fence(__ATOMIC_RELEASE, "agent");
    if (u == 0)
      __hip_atomic_store(myflag, W_, __ATOMIC_RELAXED,
                         __HIP_MEMORY_SCOPE_AGENT);
  }
}

extern "C" void kernel_launch(void* const* d_in, const int* in_sizes, int n_in,
                              void* d_out, int out_size, void* d_ws, size_t ws_size,
                              hipStream_t stream) {
  const float* x  = (const float*)d_in[0];
  const float* Wx = (const float*)d_in[1];
  const float* Wu = (const float*)d_in[2];
  const float* Wl = (const float*)d_in[3];
  const float* bb = (const float*)d_in[4];
  float* out = (float*)d_out;
  int* prog = (int*)d_ws;

  // d_ws is poisoned 0xAA before every launch -> zero the flags each time
  hipMemsetAsync(prog, 0, NROW * sizeof(int), stream);

  xproj_kernel<<<1024, 256, 0, stream>>>(x, Wx, bb, out);

  void* args[] = {(void*)&Wu, (void*)&Wl, (void*)&out, (void*)&prog};
  hipLaunchCooperativeKernel(reinterpret_cast<void*>(mdrnn_kernel),
                             dim3(NBLK), dim3(512), args, 0, stream);
}

// Round 4
// 2148.154 us; speedup vs baseline: 1.0219x; 1.0219x over previous
//
#include <hip/hip_runtime.h>

#define B_ 8
#define H_ 256
#define W_ 256
#define U_ 64
#define NROW (B_ * H_)           // 2048 rows total
#define NPIX (B_ * H_ * W_)      // 524288 pixels
#define DEPTH 32                 // LDS ring depth (power of 2)
#define WPB 8                    // waves (rows) per block
#define NBLK (NROW / WPB)        // 256 blocks == 256 CUs

__device__ __forceinline__ void lgkm_wait() {
  asm volatile("s_waitcnt lgkmcnt(0)" ::: "memory");
  __builtin_amdgcn_sched_barrier(0);
}

// Coherence-point poll: atomic RMW always reads the up-to-date value (a
// relaxed agent LOAD can legally spin on a stale L2 line on multi-XCD parts;
// an RMW cannot).
__device__ __forceinline__ int flag_rmw(int* p) {
  return __hip_atomic_fetch_add(p, 0, __ATOMIC_RELAXED,
                                __HIP_MEMORY_SCOPE_AGENT);
}

// ---------------- Phase 1: x_proj = x @ Wx + b, written in-place into out ----
__global__ __launch_bounds__(256) void xproj_kernel(
    const float* __restrict__ x, const float* __restrict__ Wx,
    const float* __restrict__ bias, float* __restrict__ out) {
  __shared__ float xs[4][64];
  const int wv = threadIdx.x >> 6;
  const int u  = threadIdx.x & 63;

  float wx[64];
#pragma unroll
  for (int k = 0; k < 64; ++k) wx[k] = Wx[k * 64 + u];  // column u of Wx
  const float bu = bias[u];

  const int stride = gridDim.x * 4;
  for (int n = blockIdx.x * 4 + wv; n < NPIX; n += stride) {
    xs[wv][u] = x[(size_t)n * 64 + u];   // stage pixel vector (coalesced)
    lgkm_wait();
    float a0 = bu, a1 = 0.f, a2 = 0.f, a3 = 0.f;
    const float4* xv4 = (const float4*)(&xs[wv][0]);
#pragma unroll
    for (int kk = 0; kk < 16; ++kk) {    // uniform-address b128 broadcasts
      float4 v = xv4[kk];
      a0 = fmaf(v.x, wx[4 * kk + 0], a0);
      a1 = fmaf(v.y, wx[4 * kk + 1], a1);
      a2 = fmaf(v.z, wx[4 * kk + 2], a2);
      a3 = fmaf(v.w, wx[4 * kk + 3], a3);
    }
    out[(size_t)n * 64 + u] = (a0 + a1) + (a2 + a3);
  }
}

// ---------------- Phase 2: cooperative pipelined 2D recurrence ---------------
// Block = 8 consecutive rows of one image. Intra-block handoffs via LDS ring;
// cross-block handoffs via coherence-point RMW flags + agent-scope data with
// a delayed-flag release protocol. XCD swizzle: image = bk&7 so a chain's 32
// blocks share one XCD (32 CUs) under round-robin dispatch.
__global__ __launch_bounds__(512, 2) void mdrnn_kernel(
    const float* __restrict__ Wu_g, const float* __restrict__ Wl_g,
    float* out, int* gflag) {
  __shared__ float ring[WPB][DEPTH][U_];
  __shared__ float upstage[2][U_];      // wave0 cross-block staging (dbuf)
  __shared__ int prodf[WPB];
  __shared__ int consf[WPB];

  const int wv = threadIdx.x >> 6;
  const int u  = threadIdx.x & 63;
  const int bk = blockIdx.x;
  const int b  = bk & 7;                     // image -> XCD (round-robin)
  const int r  = ((bk >> 3) << 3) + wv;      // row in image (chain pos * 8 + wv)
  const bool top      = (r == 0);
  const bool wave0    = (wv == 0);
  const bool wave7    = (wv == WPB - 1);
  const bool has_down = wave7 && (r < H_ - 1);

  float wu[U_], wl[U_];
#pragma unroll
  for (int k = 0; k < U_; ++k) {
    wu[k] = Wu_g[k * U_ + u];  // column u of Wu
    wl[k] = Wl_g[k * U_ + u];  // column u of Wl
  }

  float* myrow = out + (size_t)(b * H_ + r) * (W_ * U_);
  const float* uprow = out + (size_t)(b * H_ + r - 1) * (W_ * U_);
  int* myflag = gflag + b * H_ + r;
  int* upflag = gflag + b * H_ + r - 1;

  // ---- init LDS
  ring[wv][DEPTH - 1][u] = 0.f;              // left vector for j==0
  if (wv == 0) { upstage[0][u] = 0.f; upstage[1][u] = 0.f; }
  if (threadIdx.x < WPB) { prodf[threadIdx.x] = 0; consf[threadIdx.x] = 0; }
  __syncthreads();

  int gseen = 0, pseen = 0, cseen = 0;
  float xpv = myrow[u];                      // x_proj for cell 0
  float upv_reg = 0.f;

  if (wave0 && !top) {                       // stage cross-block up for cell 0
    while ((gseen = flag_rmw(upflag)) < 1) {}
    __builtin_amdgcn_fence(__ATOMIC_ACQUIRE, "agent");
    upstage[0][u] = __hip_atomic_load(uprow + u, __ATOMIC_RELAXED,
                                      __HIP_MEMORY_SCOPE_AGENT);
  }

  for (int j = 0; j < W_; ++j) {
    // ---- A: wait for up-row cell j (intra-block LDS ring; LDS can't be stale)
    if (!wave0) {
      if (pseen < j + 1) {
        while ((pseen = __hip_atomic_load(&prodf[wv - 1], __ATOMIC_RELAXED,
                                          __HIP_MEMORY_SCOPE_WORKGROUP)) < j + 1) {}
      }
      __builtin_amdgcn_fence(__ATOMIC_ACQUIRE, "workgroup");
    }
    const float* upp = wave0 ? &upstage[j & 1][0]
                             : &ring[wv - 1][j & (DEPTH - 1)][0];
    const float* lfp = &ring[wv][(j + DEPTH - 1) & (DEPTH - 1)][0];

    // ---- ring back-pressure: don't overwrite a slot the consumer hasn't read
    if (!wave7 && j >= DEPTH) {
      const int need = j - DEPTH + 1;
      if (cseen < need) {
        while ((cseen = __hip_atomic_load(&consf[wv], __ATOMIC_RELAXED,
                                          __HIP_MEMORY_SCOPE_WORKGROUP)) < need) {}
      }
    }

    // ---- B: prefetch next cell's inputs (latency hidden by FMAs)
    float xpv_n = 0.f;
    bool stage_next = false;
    if (j < W_ - 1) {
      xpv_n = myrow[(size_t)(j + 1) * U_ + u];
      if (wave0 && !top) {
        if (gseen < j + 2) {
          while ((gseen = flag_rmw(upflag)) < j + 2) {}
        }
        __builtin_amdgcn_fence(__ATOMIC_ACQUIRE, "agent");
        upv_reg = __hip_atomic_load(uprow + (size_t)(j + 1) * U_ + u,
                                    __ATOMIC_RELAXED, __HIP_MEMORY_SCOPE_AGENT);
        stage_next = true;
      }
    }

    // ---- C: cell compute (uniform-address LDS broadcasts, conflict-free)
    float a0 = xpv, a1 = 0.f, a2 = 0.f, a3 = 0.f;
    const float4* up4 = (const float4*)upp;
    const float4* lf4 = (const float4*)lfp;
#pragma unroll
    for (int kk = 0; kk < 16; ++kk) {
      float4 uv = up4[kk];
      float4 lv = lf4[kk];
      a0 = fmaf(uv.x, wu[4 * kk + 0], a0);
      a1 = fmaf(uv.y, wu[4 * kk + 1], a1);
      a2 = fmaf(uv.z, wu[4 * kk + 2], a2);
      a3 = fmaf(uv.w, wu[4 * kk + 3], a3);
      a0 = fmaf(lv.x, wl[4 * kk + 0], a0);
      a1 = fmaf(lv.y, wl[4 * kk + 1], a1);
      a2 = fmaf(lv.z, wl[4 * kk + 2], a2);
      a3 = fmaf(lv.w, wl[4 * kk + 3], a3);
    }
    const float aout = tanhf((a0 + a1) + (a2 + a3));

    // ---- D: publish — LDS ring FIRST (consumer wake latency is critical
    // path), then ONE workgroup release fence ordering {this cell's ring
    // reads, the ring write} before BOTH flag stores (prodf + consf ack).
    ring[wv][j & (DEPTH - 1)][u] = aout;
    __builtin_amdgcn_fence(__ATOMIC_RELEASE, "workgroup");
    if (u == 0) {
      if (!wave7)
        __hip_atomic_store(&prodf[wv], j + 1, __ATOMIC_RELAXED,
                           __HIP_MEMORY_SCOPE_WORKGROUP);
      if (!wave0)                            // ack consumption of up cell j
        __hip_atomic_store(&consf[wv - 1], j + 1, __ATOMIC_RELAXED,
                           __HIP_MEMORY_SCOPE_WORKGROUP);
    }

    // ---- E: global output store (+ cross-block delayed-flag for wave7)
    if (has_down) {
      // delayed-flag: agent fence drains stores issued >=1 cell ago (cheap),
      // then RMW-publish flag j (covers cells <= j-1), then issue cell j's
      // store (drained by the NEXT fence). RMW guarantees coherence-point
      // visibility for the consumer's RMW poll.
      __builtin_amdgcn_fence(__ATOMIC_RELEASE, "agent");
      if (u == 0 && j > 0)
        (void)__hip_atomic_fetch_max(myflag, j, __ATOMIC_RELAXED,
                                     __HIP_MEMORY_SCOPE_AGENT);
      __hip_atomic_store(myrow + (size_t)j * U_ + u, aout, __ATOMIC_RELAXED,
                         __HIP_MEMORY_SCOPE_AGENT);
    } else {
      myrow[(size_t)j * U_ + u] = aout;      // plain output store
    }

    if (stage_next) upstage[(j + 1) & 1][u] = upv_reg;
    xpv = xpv_n;
  }

  if (has_down) {                            // final drain + last flag
    __builtin_amdgcn_fence(__ATOMIC_RELEASE, "agent");
    if (u == 0)
      (void)__hip_atomic_fetch_max(myflag, W_, __ATOMIC_RELAXED,
                                   __HIP_MEMORY_SCOPE_AGENT);
  }
}

extern "C" void kernel_launch(void* const* d_in, const int* in_sizes, int n_in,
                              void* d_out, int out_size, void* d_ws, size_t ws_size,
                              hipStream_t stream) {
  const float* x  = (const float*)d_in[0];
  const float* Wx = (const float*)d_in[1];
  const float* Wu = (const float*)d_in[2];
  const float* Wl = (const float*)d_in[3];
  const float* bb = (const float*)d_in[4];
  float* out = (float*)d_out;
  int* prog = (int*)d_ws;

  // d_ws is poisoned 0xAA before every launch -> zero the flags each time
  hipMemsetAsync(prog, 0, NROW * sizeof(int), stream);

  xproj_kernel<<<2048, 256, 0, stream>>>(x, Wx, bb, out);

  void* args[] = {(void*)&Wu, (void*)&Wl, (void*)&out, (void*)&prog};
  hipLaunchCooperativeKernel(reinterpret_cast<void*>(mdrnn_kernel),
                             dim3(NBLK), dim3(512), args, 0, stream);
}

// Round 5
// 1123.176 us; speedup vs baseline: 1.9545x; 1.9126x over previous
//
#include <hip/hip_runtime.h>

#define B_ 8
#define H_ 256
#define W_ 256
#define U_ 64
#define NROW (B_ * H_)           // 2048 rows total
#define NPIX (B_ * H_ * W_)      // 524288 pixels
#define DEPTH 32                 // LDS ring depth (power of 2)
#define WPB 8                    // waves (rows) per block
#define NBLK (NROW / WPB)        // 256 blocks == 256 CUs

__device__ __forceinline__ void lgkm_wait() {
  asm volatile("s_waitcnt lgkmcnt(0)" ::: "memory");
  __builtin_amdgcn_sched_barrier(0);
}

// Broadcast lane `lane` of v to all lanes via v_readlane -> SGPR (no LDS pipe).
__device__ __forceinline__ float bcast_lane(float v, int lane) {
  return __uint_as_float(__builtin_amdgcn_readlane(__float_as_uint(v), lane));
}

// Fast tanh: 1 - 2/(e^{2z}+1). v_exp-based, ~5 VALU ops, saturates to +-1.
__device__ __forceinline__ float tanh_fast(float z) {
  float e = __expf(2.0f * z);
  return 1.0f - 2.0f * __builtin_amdgcn_rcpf(e + 1.0f);
}

// Lane-0-only coherence-point poll (single RMW per iteration, no 64-lane
// storm), result broadcast via readfirstlane.
__device__ __forceinline__ int poll_ge(int* p, int need, int u) {
  int g = 0;
  if (u == 0) {
    do {
      g = __hip_atomic_fetch_add(p, 0, __ATOMIC_RELAXED,
                                 __HIP_MEMORY_SCOPE_AGENT);
    } while (g < need);
  }
  g = __builtin_amdgcn_readfirstlane(g);
  asm volatile("" ::: "memory");   // pin subsequent loads after the poll
  return g;
}

// ---------------- Phase 1: x_proj = x @ Wx + b, written in-place into out ----
__global__ __launch_bounds__(256) void xproj_kernel(
    const float* __restrict__ x, const float* __restrict__ Wx,
    const float* __restrict__ bias, float* __restrict__ out) {
  __shared__ float xs[4][64];
  const int wv = threadIdx.x >> 6;
  const int u  = threadIdx.x & 63;

  float wx[64];
#pragma unroll
  for (int k = 0; k < 64; ++k) wx[k] = Wx[k * 64 + u];  // column u of Wx
  const float bu = bias[u];

  const int stride = gridDim.x * 4;
  for (int n = blockIdx.x * 4 + wv; n < NPIX; n += stride) {
    xs[wv][u] = x[(size_t)n * 64 + u];   // stage pixel vector (coalesced)
    lgkm_wait();
    float a0 = bu, a1 = 0.f, a2 = 0.f, a3 = 0.f;
    const float4* xv4 = (const float4*)(&xs[wv][0]);
#pragma unroll
    for (int kk = 0; kk < 16; ++kk) {
      float4 v = xv4[kk];
      a0 = fmaf(v.x, wx[4 * kk + 0], a0);
      a1 = fmaf(v.y, wx[4 * kk + 1], a1);
      a2 = fmaf(v.z, wx[4 * kk + 2], a2);
      a3 = fmaf(v.w, wx[4 * kk + 3], a3);
    }
    out[(size_t)n * 64 + u] = (a0 + a1) + (a2 + a3);
  }
}

// ---------------- Phase 2: cooperative pipelined 2D recurrence ---------------
// One wave per row. Row data moves wave->wave as DISTINCT lanes (lane k holds
// element k); the 64-way broadcast needed by the matvec happens in-register
// via v_readlane (no LDS broadcast traffic). Cross-block edges use sc1 data
// stores ordered by raw s_waitcnt vmcnt(0) (no agent fence / L2 writeback).
__global__ __launch_bounds__(512, 2) void mdrnn_kernel(
    const float* __restrict__ Wu_g, const float* __restrict__ Wl_g,
    float* out, int* gflag) {
  __shared__ float ring[WPB][DEPTH][U_];
  __shared__ int prodf[WPB];
  __shared__ int consf[WPB];

  const int wv = threadIdx.x >> 6;
  const int u  = threadIdx.x & 63;
  const int bk = blockIdx.x;
  const int b  = bk & 7;                     // image -> XCD (round-robin)
  const int r  = ((bk >> 3) << 3) + wv;      // row in image
  const bool top      = (r == 0);
  const bool wave0    = (wv == 0);
  const bool wave7    = (wv == WPB - 1);
  const bool has_down = wave7 && (r < H_ - 1);

  float wu[U_], wl[U_];
#pragma unroll
  for (int k = 0; k < U_; ++k) {
    wu[k] = Wu_g[k * U_ + u];  // column u of Wu
    wl[k] = Wl_g[k * U_ + u];  // column u of Wl
  }

  float* myrow = out + (size_t)(b * H_ + r) * (W_ * U_);
  const float* uprow = out + (size_t)(b * H_ + r - 1) * (W_ * U_);
  int* myflag = gflag + b * H_ + r;
  int* upflag = gflag + b * H_ + r - 1;

  if (threadIdx.x < WPB) { prodf[threadIdx.x] = 0; consf[threadIdx.x] = 0; }
  __syncthreads();

  int gseen = 0, pseen = 0, cseen = 0;
  float xpv = myrow[u];        // x_proj for cell 0
  float upg = 0.f;             // wave0: prefetched cross-block up value
  float lfv = 0.f;             // own previous output (lane u holds element u)

  if (wave0 && !top) {         // initial: wait for up-row cell 0
    gseen = poll_ge(upflag, 1, u);
    upg = __hip_atomic_load(uprow + u, __ATOMIC_RELAXED,
                            __HIP_MEMORY_SCOPE_AGENT);
  }

  for (int j = 0; j < W_; ++j) {
    // ---- A: obtain up-vector (lane k holds up[k])
    float upv;
    if (wave0) {
      upv = upg;                               // register (0 for top row)
    } else {
      if (pseen < j + 1) {
        while ((pseen = __hip_atomic_load(&prodf[wv - 1], __ATOMIC_RELAXED,
                                          __HIP_MEMORY_SCOPE_WORKGROUP)) < j + 1) {}
      }
      __builtin_amdgcn_fence(__ATOMIC_ACQUIRE, "workgroup");
      upv = ring[wv - 1][j & (DEPTH - 1)][u];  // single ds_read_b32
    }

    // ---- ring back-pressure (rarely taken)
    if (!wave7 && j >= DEPTH) {
      const int need = j - DEPTH + 1;
      if (cseen < need) {
        while ((cseen = __hip_atomic_load(&consf[wv], __ATOMIC_RELAXED,
                                          __HIP_MEMORY_SCOPE_WORKGROUP)) < need) {}
      }
    }

    // ---- B: prefetch next cell's inputs (latency hidden under FMA chains)
    float xpv_n = 0.f;
    if (j < W_ - 1) {
      xpv_n = myrow[(size_t)(j + 1) * U_ + u];
      if (wave0 && !top) {
        if (gseen < j + 2) gseen = poll_ge(upflag, j + 2, u);
        upg = __hip_atomic_load(uprow + (size_t)(j + 1) * U_ + u,
                                __ATOMIC_RELAXED, __HIP_MEMORY_SCOPE_AGENT);
      }
    }

    // ---- C1: LEFT matvec from registers (hides upv's ds_read latency)
    float a0 = xpv, a1 = 0.f, a2 = 0.f, a3 = 0.f;
#pragma unroll
    for (int k = 0; k < U_; k += 4) {
      a0 = fmaf(bcast_lane(lfv, k + 0), wl[k + 0], a0);
      a1 = fmaf(bcast_lane(lfv, k + 1), wl[k + 1], a1);
      a2 = fmaf(bcast_lane(lfv, k + 2), wl[k + 2], a2);
      a3 = fmaf(bcast_lane(lfv, k + 3), wl[k + 3], a3);
    }

    // ---- wave7 delayed-flag publish: cell j-1's sc1 store is ~1 cell old,
    // so vmcnt(0) is near-free; flag j covers cells <= j-1. No agent fence.
    if (has_down && j > 0) {
      asm volatile("s_waitcnt vmcnt(0)" ::: "memory");
      if (u == 0)
        (void)__hip_atomic_fetch_max(myflag, j, __ATOMIC_RELAXED,
                                     __HIP_MEMORY_SCOPE_AGENT);
    }

    // ---- C2: UP matvec
#pragma unroll
    for (int k = 0; k < U_; k += 4) {
      a0 = fmaf(bcast_lane(upv, k + 0), wu[k + 0], a0);
      a1 = fmaf(bcast_lane(upv, k + 1), wu[k + 1], a1);
      a2 = fmaf(bcast_lane(upv, k + 2), wu[k + 2], a2);
      a3 = fmaf(bcast_lane(upv, k + 3), wu[k + 3], a3);
    }
    const float aout = tanh_fast((a0 + a1) + (a2 + a3));

    // ---- D: intra-block publish (ring write -> wg release -> flags)
    ring[wv][j & (DEPTH - 1)][u] = aout;
    __builtin_amdgcn_fence(__ATOMIC_RELEASE, "workgroup");
    if (u == 0) {
      if (!wave7)
        __hip_atomic_store(&prodf[wv], j + 1, __ATOMIC_RELAXED,
                           __HIP_MEMORY_SCOPE_WORKGROUP);
      if (!wave0)
        __hip_atomic_store(&consf[wv - 1], j + 1, __ATOMIC_RELAXED,
                           __HIP_MEMORY_SCOPE_WORKGROUP);
    }

    // ---- E: global output store (sc1 on cross-block rows)
    if (has_down)
      __hip_atomic_store(myrow + (size_t)j * U_ + u, aout, __ATOMIC_RELAXED,
                         __HIP_MEMORY_SCOPE_AGENT);
    else
      myrow[(size_t)j * U_ + u] = aout;

    lfv = aout;
    xpv = xpv_n;
  }

  if (has_down) {              // final drain + last flag
    asm volatile("s_waitcnt vmcnt(0)" ::: "memory");
    if (u == 0)
      (void)__hip_atomic_fetch_max(myflag, W_, __ATOMIC_RELAXED,
                                   __HIP_MEMORY_SCOPE_AGENT);
  }
}

extern "C" void kernel_launch(void* const* d_in, const int* in_sizes, int n_in,
                              void* d_out, int out_size, void* d_ws, size_t ws_size,
                              hipStream_t stream) {
  const float* x  = (const float*)d_in[0];
  const float* Wx = (const float*)d_in[1];
  const float* Wu = (const float*)d_in[2];
  const float* Wl = (const float*)d_in[3];
  const float* bb = (const float*)d_in[4];
  float* out = (float*)d_out;
  int* prog = (int*)d_ws;

  // d_ws is poisoned 0xAA before every launch -> zero the flags each time
  hipMemsetAsync(prog, 0, NROW * sizeof(int), stream);

  xproj_kernel<<<2048, 256, 0, stream>>>(x, Wx, bb, out);

  void* args[] = {(void*)&Wu, (void*)&Wl, (void*)&out, (void*)&prog};
  hipLaunchCooperativeKernel(reinterpret_cast<void*>(mdrnn_kernel),
                             dim3(NBLK), dim3(512), args, 0, stream);
}